// Round 15
// baseline (662.013 us; speedup 1.0000x reference)
//
#include <hip/hip_runtime.h>
#include <stdint.h>

#define DEV __device__ __forceinline__

typedef __attribute__((ext_vector_type(8))) short short8v;   // 8 x bf16 bits
typedef __attribute__((ext_vector_type(4))) short short4v;   // 4 x bf16 bits
typedef __attribute__((ext_vector_type(4))) float f32x4;
typedef __attribute__((ext_vector_type(16))) float f32x16;

DEV uint16_t f2bf(float f) {
  union { float f; uint32_t u; } x; x.f = f;
  return (uint16_t)((x.u + 0x7FFFu + ((x.u >> 16) & 1u)) >> 16);  // RNE
}
DEV float bf2f(uint16_t v) {
  union { uint32_t u; float f; } x; x.u = ((uint32_t)v) << 16;
  return x.f;
}

// async global->LDS, 16B per lane. LDS dest = wave-uniform base + lane*16.
DEV void gload_lds16(const uint16_t* g, uint16_t* l) {
  __builtin_amdgcn_global_load_lds(
      (const __attribute__((address_space(1))) uint32_t*)g,
      (__attribute__((address_space(3))) uint32_t*)l, 16, 0, 0);
}

// ---------------- fp32 -> bf16 convert, 5 buffers in one launch ----------
__global__ void convert5_kernel(const float* __restrict__ x,
                                const float* __restrict__ wq,
                                const float* __restrict__ wk,
                                const float* __restrict__ wv,
                                const float* __restrict__ wo,
                                uint16_t* __restrict__ xb, uint16_t* __restrict__ wqb,
                                uint16_t* __restrict__ wkb, uint16_t* __restrict__ wvb,
                                uint16_t* __restrict__ wob, int n4) {
  const int which = blockIdx.y;
  const float* in = which == 0 ? x : which == 1 ? wq : which == 2 ? wk
                                   : which == 3 ? wv : wo;
  uint16_t* out = which == 0 ? xb : which == 1 ? wqb : which == 2 ? wkb
                                  : which == 3 ? wvb : wob;
  int i = blockIdx.x * blockDim.x + threadIdx.x;
  if (i >= n4) return;
  float4 v = reinterpret_cast<const float4*>(in)[i];
  short4v o;
  o[0] = (short)f2bf(v.x); o[1] = (short)f2bf(v.y);
  o[2] = (short)f2bf(v.z); o[3] = (short)f2bf(v.w);
  *reinterpret_cast<short4v*>(out + (size_t)i * 4) = o;
}

// ---------------- GEMM 256x256, BK=64, 2-phase pipelined -----------------
// blockIdx.z selects a 4096-wide GEMM slice: Bt/Cb advance by z*16M.
// 2 phases per K-tile (32 MFMA each, 4 barriers/tile vs 8): same region/k
// staging assignments as the 4-phase schedule, overwrite-issues moved
// after the barrier that confirms the region's reads. vmcnt(6)/tile.
template <int F32OUT>
__global__ __launch_bounds__(512, 2) void gemm256_kernel(
    const uint16_t* __restrict__ A, const uint16_t* __restrict__ Bt,
    float* __restrict__ Cf, uint16_t* __restrict__ Cb, int M, int N, int K) {
  __shared__ uint16_t smem[65536];  // 128 KB
  uint16_t* As0 = smem;
  uint16_t* As1 = smem + 16384;
  uint16_t* Bs0 = smem + 32768;
  uint16_t* Bs1 = smem + 49152;

  Bt += (size_t)blockIdx.z * 16777216;
  Cb += (size_t)blockIdx.z * 16777216;

  const int tid = threadIdx.x;
  const int lane = tid & 63, w = tid >> 6;
  const int ln16 = lane & 15, g = lane >> 4;
  const int wr = w >> 2, wc = w & 3;

  // XCD-aware bijective swizzle per slice (256 blocks, %8==0)
  const int nbx = gridDim.x;
  int bid = blockIdx.y * nbx + blockIdx.x;
  int nb = nbx * gridDim.y;
  int cpx = nb >> 3;
  int sw = (bid & 7) * cpx + (bid >> 3);
  const int m0 = (sw / nbx) * 256, n0 = (sw % nbx) * 256;

  // per-thread staging source (pre-swizzled global col)
  const int trow = tid >> 3;                               // 0..63
  const int tcol = ((tid & 7) ^ (trow & 7)) * 8;
  const uint16_t* srcA = A + (size_t)(m0 + trow) * K + tcol;
  const int brow = (w >> 2) * 64 + (w & 3) * 8 + (lane >> 3);
  const int bcol = ((lane & 7) ^ ((lane >> 3) & 7)) * 8;
  const uint16_t* srcB = Bt + (size_t)(n0 + brow) * K + bcol;
  const int dstAw = w * 512;                               // + q*4096
  const int dstBw = ((w >> 2) * 64 + (w & 3) * 8) * 64;    // + (c*128+nq*32)*64

#define STA(buf, q, kt) \
  gload_lds16(srcA + (size_t)((q) * 64) * K + (kt) * 64, (buf) + (q) * 4096 + dstAw)
#define STB(buf, nq, c, kt) \
  gload_lds16(srcB + (size_t)((c) * 128 + (nq) * 32) * K + (kt) * 64, \
              (buf) + ((c) * 128 + (nq) * 32) * 64 + dstBw)
#define LDA(buf, mq, mi, ks) \
  (*reinterpret_cast<const short8v*>( \
      (buf) + (wr * 128 + (mq) * 64 + (mi) * 16 + ln16) * 64 + \
      ((((ks) * 4 + g) ^ (ln16 & 7)) * 8)))
#define LDB(buf, nq, ni, ks) \
  (*reinterpret_cast<const short8v*>( \
      (buf) + (wc * 64 + (nq) * 32 + (ni) * 16 + ln16) * 64 + \
      ((((ks) * 4 + g) ^ (ln16 & 7)) * 8)))

  f32x4 acc[8][4];
#pragma unroll
  for (int i = 0; i < 8; ++i)
#pragma unroll
    for (int j = 0; j < 4; ++j) acc[i][j] = f32x4{0.f, 0.f, 0.f, 0.f};

  // ---- prologue (identical staging assignments to 4-phase version)
  STA(As0, 0, 0); STA(As0, 2, 0); STA(As0, 1, 0); STA(As0, 3, 0);
  STB(Bs0, 0, 0, 0); STB(Bs0, 0, 1, 0); STB(Bs0, 1, 0, 0); STB(Bs0, 1, 1, 0);
  STA(As1, 0, 1); STA(As1, 2, 1);
  STB(Bs1, 0, 0, 1); STB(Bs1, 0, 1, 1); STB(Bs1, 1, 0, 1); STB(Bs1, 1, 1, 1);
  asm volatile("s_waitcnt vmcnt(6)" ::: "memory");
  __builtin_amdgcn_sched_barrier(0);
  __builtin_amdgcn_s_barrier();

  uint16_t *Ac = As0, *An = As1, *Bc = Bs0, *Bn = Bs1;
  short8v af[4][2], bf0[2][2], bf1[2][2];

  const int NT = K >> 6;
  for (int t = 0; t < NT; ++t) {
    const int k1 = (t + 1 < NT) ? t + 1 : NT - 1;
    const int k2 = (t + 2 < NT) ? t + 2 : NT - 1;
    // ======== Phase A: mq0 x (nq0..nq3), 32 MFMA ========
#pragma unroll
    for (int mi = 0; mi < 4; ++mi) { af[mi][0] = LDA(Ac, 0, mi, 0); af[mi][1] = LDA(Ac, 0, mi, 1); }
#pragma unroll
    for (int ni = 0; ni < 2; ++ni) { bf0[ni][0] = LDB(Bc, 0, ni, 0); bf0[ni][1] = LDB(Bc, 0, ni, 1); }
#pragma unroll
    for (int ni = 0; ni < 2; ++ni) { bf1[ni][0] = LDB(Bc, 1, ni, 0); bf1[ni][1] = LDB(Bc, 1, ni, 1); }
    STA(An, 1, k1); STA(An, 3, k1);
    __builtin_amdgcn_s_barrier();
    asm volatile("s_waitcnt lgkmcnt(0)" ::: "memory");
    __builtin_amdgcn_sched_barrier(0);
    __builtin_amdgcn_s_setprio(1);
#pragma unroll
    for (int ks = 0; ks < 2; ++ks)
#pragma unroll
      for (int mi = 0; mi < 4; ++mi) {
#pragma unroll
        for (int ni = 0; ni < 2; ++ni)
          acc[mi][ni] = __builtin_amdgcn_mfma_f32_16x16x32_bf16(af[mi][ks], bf0[ni][ks], acc[mi][ni], 0, 0, 0);
#pragma unroll
        for (int ni = 0; ni < 2; ++ni)
          acc[mi][2 + ni] = __builtin_amdgcn_mfma_f32_16x16x32_bf16(af[mi][ks], bf1[ni][ks], acc[mi][2 + ni], 0, 0, 0);
      }
    __builtin_amdgcn_s_setprio(0);
    __builtin_amdgcn_s_barrier();
    // ======== Phase B: mq1 x (nq0..nq3), 32 MFMA ========
    // All Ac-quad{0,2} / Bc reads confirmed by phase-A end barrier.
    STA(Ac, 0, k2); STA(Ac, 2, k2);
    STB(Bc, 0, 0, k2); STB(Bc, 0, 1, k2);
    STB(Bc, 1, 0, k2); STB(Bc, 1, 1, k2);
#pragma unroll
    for (int mi = 0; mi < 4; ++mi) { af[mi][0] = LDA(Ac, 1, mi, 0); af[mi][1] = LDA(Ac, 1, mi, 1); }
    __builtin_amdgcn_s_barrier();
    asm volatile("s_waitcnt lgkmcnt(0)" ::: "memory");
    __builtin_amdgcn_sched_barrier(0);
    __builtin_amdgcn_s_setprio(1);
#pragma unroll
    for (int ks = 0; ks < 2; ++ks)
#pragma unroll
      for (int mi = 0; mi < 4; ++mi) {
#pragma unroll
        for (int ni = 0; ni < 2; ++ni)
          acc[4 + mi][ni] = __builtin_amdgcn_mfma_f32_16x16x32_bf16(af[mi][ks], bf0[ni][ks], acc[4 + mi][ni], 0, 0, 0);
#pragma unroll
        for (int ni = 0; ni < 2; ++ni)
          acc[4 + mi][2 + ni] = __builtin_amdgcn_mfma_f32_16x16x32_bf16(af[mi][ks], bf1[ni][ks], acc[4 + mi][2 + ni], 0, 0, 0);
      }
    __builtin_amdgcn_s_setprio(0);
    asm volatile("s_waitcnt vmcnt(6)" ::: "memory");
    __builtin_amdgcn_sched_barrier(0);
    __builtin_amdgcn_s_barrier();
    // swap buffers
    uint16_t* tp = Ac; Ac = An; An = tp;
    tp = Bc; Bc = Bn; Bn = tp;
  }

  // ---- epilogue: C/D layout col=lane&15, row=(lane>>4)*4+r
#pragma unroll
  for (int gmi = 0; gmi < 8; ++gmi)
#pragma unroll
    for (int r = 0; r < 4; ++r) {
      int row = m0 + wr * 128 + gmi * 16 + g * 4 + r;
#pragma unroll
      for (int gni = 0; gni < 4; ++gni) {
        int col = n0 + wc * 64 + gni * 16 + ln16;
        if (F32OUT)
          Cf[(size_t)row * 4096 + col] = acc[gmi][gni][r];
        else
          Cb[(size_t)row * 4096 + col] = (uint16_t)f2bf(acc[gmi][gni][r]);
      }
    }
#undef STA
#undef STB
#undef LDA
#undef LDB
}

// ---------------- RoPE in-place on (B,S,H,128) bf16, short8 vectorized ----
__global__ void rope_kernel(uint16_t* __restrict__ buf,
                            const float* __restrict__ cost,
                            const float* __restrict__ sint) {
  int idx = blockIdx.x * blockDim.x + threadIdx.x;  // 2*2048*32*8 = 1048576
  int j8 = idx & 7;
  int h = (idx >> 3) & 31;
  int s = (idx >> 8) & 2047;
  int b = idx >> 19;
  size_t base = ((size_t)(b * 2048 + s)) * 4096 + h * 128 + j8 * 8;
  short8v x1 = *reinterpret_cast<const short8v*>(buf + base);
  short8v x2 = *reinterpret_cast<const short8v*>(buf + base + 64);
  float4 c0 = *reinterpret_cast<const float4*>(cost + s * 64 + j8 * 8);
  float4 c1 = *reinterpret_cast<const float4*>(cost + s * 64 + j8 * 8 + 4);
  float4 s0 = *reinterpret_cast<const float4*>(sint + s * 64 + j8 * 8);
  float4 s1 = *reinterpret_cast<const float4*>(sint + s * 64 + j8 * 8 + 4);
  float c[8] = {c0.x, c0.y, c0.z, c0.w, c1.x, c1.y, c1.z, c1.w};
  float sn[8] = {s0.x, s0.y, s0.z, s0.w, s1.x, s1.y, s1.z, s1.w};
  short8v o1, o2;
#pragma unroll
  for (int e = 0; e < 8; ++e) {
    float a = bf2f((uint16_t)x1[e]);
    float bb = bf2f((uint16_t)x2[e]);
    o1[e] = (short)f2bf(a * c[e] - bb * sn[e]);
    o2[e] = (short)f2bf(bb * c[e] + a * sn[e]);
  }
  *reinterpret_cast<short8v*>(buf + base) = o1;
  *reinterpret_cast<short8v*>(buf + base + 64) = o2;
}

// ---------------- causal flash attention, 32x32 swapped-QK^T -------------
// 4 waves x 32 q-rows, uniform pairing (block p does q-tiles 15-p then p
// = 34 K-tiles), double-buffered K/V LDS, 1 barrier/tile, K staged via
// global_load_lds (pre-swizzled source), V reg-staged. RoPE-on-Q fused
// with scale*log2e folded in.
__global__ __launch_bounds__(256, 2) void flash_kernel(
    const uint16_t* __restrict__ Q, const uint16_t* __restrict__ K,
    const uint16_t* __restrict__ V, uint16_t* __restrict__ O,
    const float* __restrict__ cost, const float* __restrict__ sint) {
  constexpr int S = 2048, HID = 4096;
  __shared__ uint16_t Ks[2][64 * 128];   // [k][d], swizzled
  __shared__ uint16_t Vt[2][128 * 64];   // [d][k] transposed, swizzled

  const int tid = threadIdx.x;
  const int lane = tid & 63, w = tid >> 6;
  const int l31 = lane & 31, hi = lane >> 5;
  const int bh = blockIdx.x;            // bh fastest -> same head same XCD
  const int b = bh >> 5, h = bh & 31;
  const int pr = blockIdx.y;            // pair id 0..7
  const size_t base = (size_t)b * S * HID + (size_t)h * 128;
  const int swz = (l31 & 7) << 3;       // frag-read swizzle for this lane

  // ---- K staging via gload_lds: instr i stages rows w*16+i*4..+3.
  const int kr_g = lane >> 4;                       // row-in-group 0..3
  const int kre = w * 16 + kr_g;                    // rows for i even
  const int kro = w * 16 + 4 + kr_g;                // rows for i odd
  const uint16_t* kse = K + base + (size_t)kre * HID + (((lane & 15) ^ (kr_g & 7)) * 8);
  const uint16_t* kso = K + base + (size_t)kro * HID + (((lane & 15) ^ ((4 + kr_g) & 7)) * 8);
  // V staging geometry (reg transpose)
  const int vk4 = tid & 15;        // k/4
  const int vdc = tid >> 4;        // d-chunk (0..15)

#define STAGEK(dst, kb0)                                                     \
  do {                                                                       \
    gload_lds16(kse + (size_t)(kb0) * HID,       (dst) + (w * 16 + 0) * 128);  \
    gload_lds16(kso + (size_t)(kb0) * HID,       (dst) + (w * 16 + 4) * 128);  \
    gload_lds16(kse + (size_t)((kb0) + 8) * HID, (dst) + (w * 16 + 8) * 128);  \
    gload_lds16(kso + (size_t)((kb0) + 8) * HID, (dst) + (w * 16 + 12) * 128); \
  } while (0)

  const float cl2e = 0.12751025f;  // (1/sqrt(128)) * log2(e), folded into Q

  for (int pass = 0; pass < 2; ++pass) {
    const int bt = pass ? pr : 15 - pr;   // long q-tile first
    const int q0 = bt * 128;
    const int q0w = q0 + w * 32;

    // ---- Q frags, fused RoPE x (scale*log2e)
    short8v qf[8];
    {
      const int srow = q0w + l31;
      const uint16_t* qrow = Q + base + (size_t)srow * HID + hi * 8;
      const float* cr = cost + srow * 64 + hi * 8;
      const float* sr = sint + srow * 64 + hi * 8;
#pragma unroll
      for (int c = 0; c < 4; ++c) {
        short8v x1 = *reinterpret_cast<const short8v*>(qrow + c * 16);
        short8v x2 = *reinterpret_cast<const short8v*>(qrow + 64 + c * 16);
        float4 cA = *reinterpret_cast<const float4*>(cr + c * 16);
        float4 cB = *reinterpret_cast<const float4*>(cr + c * 16 + 4);
        float4 sA = *reinterpret_cast<const float4*>(sr + c * 16);
        float4 sB = *reinterpret_cast<const float4*>(sr + c * 16 + 4);
        float cc[8] = {cA.x, cA.y, cA.z, cA.w, cB.x, cB.y, cB.z, cB.w};
        float ss[8] = {sA.x, sA.y, sA.z, sA.w, sB.x, sB.y, sB.z, sB.w};
        short8v o1, o2;
#pragma unroll
        for (int e = 0; e < 8; ++e) {
          float a = bf2f((uint16_t)x1[e]) * cl2e;
          float bb = bf2f((uint16_t)x2[e]) * cl2e;
          o1[e] = (short)f2bf(a * cc[e] - bb * ss[e]);
          o2[e] = (short)f2bf(bb * cc[e] + a * ss[e]);
        }
        qf[c] = o1; qf[c + 4] = o2;
      }
    }

    f32x16 o[4];
#pragma unroll
    for (int db = 0; db < 4; ++db)
#pragma unroll
      for (int r = 0; r < 16; ++r) o[db][r] = 0.f;
    float m_run = -1e30f, l_run = 0.f;

    short8v vp[4];  // V prefetch registers

    // ---- prologue: stage tile 0 into buffer 0
    STAGEK(&Ks[0][0], 0);
#pragma unroll
    for (int j = 0; j < 4; ++j)
      vp[j] = *reinterpret_cast<const short8v*>(
          V + base + (size_t)(4 * vk4 + j) * HID + vdc * 8);
#pragma unroll
    for (int e = 0; e < 8; ++e) {
      int row = vdc * 8 + e;
      short4v pk; pk[0] = vp[0][e]; pk[1] = vp[1][e]; pk[2] = vp[2][e]; pk[3] = vp[3][e];
      *reinterpret_cast<short4v*>(&Vt[0][0] + row * 64 + ((vk4 * 4) ^ ((row & 7) << 3))) = pk;
    }
    __syncthreads();

    const int ntiles = bt * 2 + 2;
    for (int kt = 0; kt < ntiles; ++kt) {
      const int kb = kt * 64;
      const bool havenext = (kt + 1 < ntiles);
      uint16_t* ksc = &Ks[kt & 1][0];
      uint16_t* vtc = &Vt[kt & 1][0];
      uint16_t* ksn = &Ks[(kt + 1) & 1][0];
      uint16_t* vtn = &Vt[(kt + 1) & 1][0];
      // ---- stage next tile: K async -> LDS[nxt]; V global -> regs
      if (havenext) {
        STAGEK(ksn, kb + 64);
#pragma unroll
        for (int j = 0; j < 4; ++j)
          vp[j] = *reinterpret_cast<const short8v*>(
              V + base + (size_t)(kb + 64 + 4 * vk4 + j) * HID + vdc * 8);
      }

      if (kb <= q0w + 31) {
        f32x16 s0, s1;
#pragma unroll
        for (int r = 0; r < 16; ++r) { s0[r] = 0.f; s1[r] = 0.f; }
        __builtin_amdgcn_s_setprio(1);
#pragma unroll
        for (int c = 0; c < 8; ++c) {
          int col = c * 16 + hi * 8;
          short8v kf0 = *reinterpret_cast<const short8v*>(ksc + l31 * 128 + (col ^ swz));
          short8v kf1 = *reinterpret_cast<const short8v*>(ksc + (32 + l31) * 128 + (col ^ swz));
          s0 = __builtin_amdgcn_mfma_f32_32x32x16_bf16(kf0, qf[c], s0, 0, 0, 0);
          s1 = __builtin_amdgcn_mfma_f32_32x32x16_bf16(kf1, qf[c], s1, 0, 0, 0);
        }
        __builtin_amdgcn_s_setprio(0);
        // (scores already in exp2 domain - scale folded into Q)
        if (kb + 63 > q0w) {
          const int qg = q0w + l31;
#pragma unroll
          for (int r = 0; r < 16; ++r) {
            int kl = (r & 3) + 8 * (r >> 2) + 4 * hi;
            if (kb + kl > qg) s0[r] = -1e30f;
            if (kb + 32 + kl > qg) s1[r] = -1e30f;
          }
        }
        float mx = s0[0];
#pragma unroll
        for (int r = 1; r < 16; ++r) mx = fmaxf(mx, s0[r]);
#pragma unroll
        for (int r = 0; r < 16; ++r) mx = fmaxf(mx, s1[r]);
        mx = fmaxf(mx, __shfl_xor(mx, 32));
        if (__any(mx > m_run + 8.0f)) {  // defer-max (T13)
          float nm = fmaxf(m_run, mx);
          float f = __builtin_amdgcn_exp2f(m_run - nm);
          l_run *= f;
#pragma unroll
          for (int db = 0; db < 4; ++db)
#pragma unroll
            for (int r = 0; r < 16; ++r) o[db][r] *= f;
          m_run = nm;
        }
        float rs = 0.f;
#pragma unroll
        for (int r = 0; r < 16; ++r) { s0[r] = __builtin_amdgcn_exp2f(s0[r] - m_run); rs += s0[r]; }
#pragma unroll
        for (int r = 0; r < 16; ++r) { s1[r] = __builtin_amdgcn_exp2f(s1[r] - m_run); rs += s1[r]; }
        rs += __shfl_xor(rs, 32);
        l_run += rs;
        uint32_t c0[8], c1[8];
#pragma unroll
        for (int i = 0; i < 4; ++i) {
          asm("v_cvt_pk_bf16_f32 %0, %1, %2" : "=v"(c0[i])     : "v"(s0[4 * i]),     "v"(s0[4 * i + 1]));
          asm("v_cvt_pk_bf16_f32 %0, %1, %2" : "=v"(c1[i])     : "v"(s0[4 * i + 2]), "v"(s0[4 * i + 3]));
          asm("v_cvt_pk_bf16_f32 %0, %1, %2" : "=v"(c0[4 + i]) : "v"(s1[4 * i]),     "v"(s1[4 * i + 1]));
          asm("v_cvt_pk_bf16_f32 %0, %1, %2" : "=v"(c1[4 + i]) : "v"(s1[4 * i + 2]), "v"(s1[4 * i + 3]));
        }
        short8v pa[4];
#pragma unroll
        for (int t = 0; t < 4; ++t) {
          int st = t >> 1, ts = t & 1;
          uint32_t a0 = c0[st * 4 + 2 * ts],     a1 = c1[st * 4 + 2 * ts];
          uint32_t b0 = c0[st * 4 + 2 * ts + 1], b1 = c1[st * 4 + 2 * ts + 1];
          uint32_t sb0 = (uint32_t)__shfl_xor((int)b0, 32);
          uint32_t sb1 = (uint32_t)__shfl_xor((int)b1, 32);
          uint32_t sa0 = (uint32_t)__shfl_xor((int)a0, 32);
          uint32_t sa1 = (uint32_t)__shfl_xor((int)a1, 32);
          union { uint32_t u[4]; short8v v; } pk;
          pk.u[0] = hi ? sb0 : a0;
          pk.u[1] = hi ? sb1 : a1;
          pk.u[2] = hi ? b0 : sa0;
          pk.u[3] = hi ? b1 : sa1;
          pa[t] = pk.v;
        }
        __builtin_amdgcn_s_setprio(1);
#pragma unroll
        for (int t = 0; t < 4; ++t) {
          int col = t * 16 + hi * 8;
#pragma unroll
          for (int db = 0; db < 4; ++db) {
            short8v vf = *reinterpret_cast<const short8v*>(
                vtc + (db * 32 + l31) * 64 + (col ^ swz));
            o[db] = __builtin_amdgcn_mfma_f32_32x32x16_bf16(vf, pa[t], o[db], 0, 0, 0);
          }
        }
        __builtin_amdgcn_s_setprio(0);
      }
      // ---- write prefetched V into the other buffer
      if (havenext) {
#pragma unroll
        for (int e = 0; e < 8; ++e) {
          int row = vdc * 8 + e;
          short4v pk; pk[0] = vp[0][e]; pk[1] = vp[1][e]; pk[2] = vp[2][e]; pk[3] = vp[3][e];
          *reinterpret_cast<short4v*>(vtn + row * 64 + ((vk4 * 4) ^ ((row & 7) << 3))) = pk;
        }
      }
      __syncthreads();  // one barrier per tile (drains gload_lds + ds_writes)
    }

    float inv = 1.f / l_run;
    uint16_t* orow = O + base + (size_t)(q0w + l31) * HID;
#pragma unroll
    for (int db = 0; db < 4; ++db)
#pragma unroll
      for (int rq = 0; rq < 4; ++rq) {
        short4v st4;
#pragma unroll
        for (int e = 0; e < 4; ++e) st4[e] = (short)f2bf(o[db][rq * 4 + e] * inv);
        *reinterpret_cast<short4v*>(orow + db * 32 + rq * 8 + hi * 4) = st4;
      }
  }
#undef STAGEK
}

// ---------------- launch ----------------
extern "C" void kernel_launch(void* const* d_in, const int* in_sizes, int n_in,
                              void* d_out, int out_size, void* d_ws, size_t ws_size,
                              hipStream_t stream) {
  const float* x    = (const float*)d_in[0];
  const float* cosb = (const float*)d_in[1];
  const float* sinb = (const float*)d_in[2];
  const float* wq   = (const float*)d_in[3];
  const float* wk   = (const float*)d_in[4];
  const float* wv   = (const float*)d_in[5];
  const float* wo   = (const float*)d_in[6];
  float* out = (float*)d_out;

  const size_t BUF = 33554432;  // 16.7M bf16 elements = 32 MiB
  if (ws_size < 8 * BUF) return;
  char* ws = (char*)d_ws;
  uint16_t* xb  = (uint16_t*)(ws + 0 * BUF);  // also reused as attn-out
  uint16_t* wqb = (uint16_t*)(ws + 1 * BUF);  // wqb/wkb/wvb contiguous
  uint16_t* wkb = (uint16_t*)(ws + 2 * BUF);
  uint16_t* wvb = (uint16_t*)(ws + 3 * BUF);
  uint16_t* wob = (uint16_t*)(ws + 4 * BUF);
  uint16_t* qb  = (uint16_t*)(ws + 5 * BUF);  // qb/kb/vb contiguous
  uint16_t* kb  = (uint16_t*)(ws + 6 * BUF);
  uint16_t* vb  = (uint16_t*)(ws + 7 * BUF);
  uint16_t* ab  = xb;

  const int nElem = 2 * 2048 * 4096;  // 16,777,216 (= 4096*4096 too)
  dim3 cgrid(nElem / 4 / 256, 5);
  convert5_kernel<<<cgrid, 256, 0, stream>>>(x, wq, wk, wv, wo,
                                             xb, wqb, wkb, wvb, wob, nElem / 4);

  // QKV projections: one 3D dispatch, z = {q,k,v} slice (per-slice locality)
  dim3 gqkv(16, 16, 3), gblk(512);
  gemm256_kernel<0><<<gqkv, gblk, 0, stream>>>(xb, wqb, nullptr, qb, 4096, 4096, 4096);

  // RoPE only on K (Q rope fused into flash)
  dim3 rgrid(1048576 / 256);
  rope_kernel<<<rgrid, 256, 0, stream>>>(kb, cosb, sinb);

  dim3 fgrid(64, 8);  // (B*H fastest, q-tile pairs): head -> one XCD
  flash_kernel<<<fgrid, 256, 0, stream>>>(qb, kb, vb, ab, cosb, sinb);

  dim3 ggrid(16, 16, 1);
  gemm256_kernel<1><<<ggrid, gblk, 0, stream>>>(ab, wob, out, nullptr, 4096, 4096, 4096);
}

// Round 16
// 642.414 us; speedup vs baseline: 1.0305x; 1.0305x over previous
//
#include <hip/hip_runtime.h>
#include <stdint.h>

#define DEV __device__ __forceinline__

typedef __attribute__((ext_vector_type(8))) short short8v;   // 8 x bf16 bits
typedef __attribute__((ext_vector_type(4))) short short4v;   // 4 x bf16 bits
typedef __attribute__((ext_vector_type(4))) float f32x4;
typedef __attribute__((ext_vector_type(16))) float f32x16;

DEV uint16_t f2bf(float f) {
  union { float f; uint32_t u; } x; x.f = f;
  return (uint16_t)((x.u + 0x7FFFu + ((x.u >> 16) & 1u)) >> 16);  // RNE
}
DEV float bf2f(uint16_t v) {
  union { uint32_t u; float f; } x; x.u = ((uint32_t)v) << 16;
  return x.f;
}

// async global->LDS, 16B per lane. LDS dest = wave-uniform base + lane*16.
DEV void gload_lds16(const uint16_t* g, uint16_t* l) {
  __builtin_amdgcn_global_load_lds(
      (const __attribute__((address_space(1))) uint32_t*)g,
      (__attribute__((address_space(3))) uint32_t*)l, 16, 0, 0);
}

// ---------------- fp32 -> bf16 convert, 5 buffers in one launch ----------
__global__ void convert5_kernel(const float* __restrict__ x,
                                const float* __restrict__ wq,
                                const float* __restrict__ wk,
                                const float* __restrict__ wv,
                                const float* __restrict__ wo,
                                uint16_t* __restrict__ xb, uint16_t* __restrict__ wqb,
                                uint16_t* __restrict__ wkb, uint16_t* __restrict__ wvb,
                                uint16_t* __restrict__ wob, int n4) {
  const int which = blockIdx.y;
  const float* in = which == 0 ? x : which == 1 ? wq : which == 2 ? wk
                                   : which == 3 ? wv : wo;
  uint16_t* out = which == 0 ? xb : which == 1 ? wqb : which == 2 ? wkb
                                  : which == 3 ? wvb : wob;
  int i = blockIdx.x * blockDim.x + threadIdx.x;
  if (i >= n4) return;
  float4 v = reinterpret_cast<const float4*>(in)[i];
  short4v o;
  o[0] = (short)f2bf(v.x); o[1] = (short)f2bf(v.y);
  o[2] = (short)f2bf(v.z); o[3] = (short)f2bf(v.w);
  *reinterpret_cast<short4v*>(out + (size_t)i * 4) = o;
}

// ---------------- GEMM 256x256, BK=64, 4-phase pipelined -----------------
// blockIdx.z selects a 4096-wide GEMM slice: Bt/Cb advance by z*16M.
// Swizzle is per-slice (x,y only) -> per-slice XCD locality preserved,
// while one dispatch lets blocks pipeline across slices.
template <int F32OUT>
__global__ __launch_bounds__(512, 2) void gemm256_kernel(
    const uint16_t* __restrict__ A, const uint16_t* __restrict__ Bt,
    float* __restrict__ Cf, uint16_t* __restrict__ Cb, int M, int N, int K) {
  __shared__ uint16_t smem[65536];  // 128 KB
  uint16_t* As0 = smem;
  uint16_t* As1 = smem + 16384;
  uint16_t* Bs0 = smem + 32768;
  uint16_t* Bs1 = smem + 49152;

  Bt += (size_t)blockIdx.z * 16777216;
  Cb += (size_t)blockIdx.z * 16777216;

  const int tid = threadIdx.x;
  const int lane = tid & 63, w = tid >> 6;
  const int ln16 = lane & 15, g = lane >> 4;
  const int wr = w >> 2, wc = w & 3;

  // XCD-aware bijective swizzle per slice (256 blocks, %8==0)
  const int nbx = gridDim.x;
  int bid = blockIdx.y * nbx + blockIdx.x;
  int nb = nbx * gridDim.y;
  int cpx = nb >> 3;
  int sw = (bid & 7) * cpx + (bid >> 3);
  const int m0 = (sw / nbx) * 256, n0 = (sw % nbx) * 256;

  // per-thread staging source (pre-swizzled global col)
  const int trow = tid >> 3;                               // 0..63
  const int tcol = ((tid & 7) ^ (trow & 7)) * 8;
  const uint16_t* srcA = A + (size_t)(m0 + trow) * K + tcol;
  const int brow = (w >> 2) * 64 + (w & 3) * 8 + (lane >> 3);
  const int bcol = ((lane & 7) ^ ((lane >> 3) & 7)) * 8;
  const uint16_t* srcB = Bt + (size_t)(n0 + brow) * K + bcol;
  const int dstAw = w * 512;                               // + q*4096
  const int dstBw = ((w >> 2) * 64 + (w & 3) * 8) * 64;    // + (c*128+nq*32)*64

#define STA(buf, q, kt) \
  gload_lds16(srcA + (size_t)((q) * 64) * K + (kt) * 64, (buf) + (q) * 4096 + dstAw)
#define STB(buf, nq, c, kt) \
  gload_lds16(srcB + (size_t)((c) * 128 + (nq) * 32) * K + (kt) * 64, \
              (buf) + ((c) * 128 + (nq) * 32) * 64 + dstBw)
#define LDA(buf, mq, mi, ks) \
  (*reinterpret_cast<const short8v*>( \
      (buf) + (wr * 128 + (mq) * 64 + (mi) * 16 + ln16) * 64 + \
      ((((ks) * 4 + g) ^ (ln16 & 7)) * 8)))
#define LDB(buf, nq, ni, ks) \
  (*reinterpret_cast<const short8v*>( \
      (buf) + (wc * 64 + (nq) * 32 + (ni) * 16 + ln16) * 64 + \
      ((((ks) * 4 + g) ^ (ln16 & 7)) * 8)))

  f32x4 acc[8][4];
#pragma unroll
  for (int i = 0; i < 8; ++i)
#pragma unroll
    for (int j = 0; j < 4; ++j) acc[i][j] = f32x4{0.f, 0.f, 0.f, 0.f};

  // ---- prologue
  STA(As0, 0, 0); STA(As0, 2, 0); STA(As0, 1, 0); STA(As0, 3, 0);
  STB(Bs0, 0, 0, 0); STB(Bs0, 0, 1, 0); STB(Bs0, 1, 0, 0); STB(Bs0, 1, 1, 0);
  STA(As1, 0, 1); STA(As1, 2, 1);
  STB(Bs1, 0, 0, 1); STB(Bs1, 0, 1, 1); STB(Bs1, 1, 0, 1); STB(Bs1, 1, 1, 1);
  asm volatile("s_waitcnt vmcnt(6)" ::: "memory");
  __builtin_amdgcn_sched_barrier(0);
  __builtin_amdgcn_s_barrier();

  uint16_t *Ac = As0, *An = As1, *Bc = Bs0, *Bn = Bs1;
  short8v af[4][2], bf0[2][2], bf1[2][2];

  const int NT = K >> 6;
  for (int t = 0; t < NT; ++t) {
    const int k1 = (t + 1 < NT) ? t + 1 : NT - 1;
    const int k2 = (t + 2 < NT) ? t + 2 : NT - 1;
    // ======== P1: (mq0, nq0) ========
#pragma unroll
    for (int mi = 0; mi < 4; ++mi) { af[mi][0] = LDA(Ac, 0, mi, 0); af[mi][1] = LDA(Ac, 0, mi, 1); }
#pragma unroll
    for (int ni = 0; ni < 2; ++ni) { bf0[ni][0] = LDB(Bc, 0, ni, 0); bf0[ni][1] = LDB(Bc, 0, ni, 1); }
    STA(An, 1, k1); STA(An, 3, k1);
    __builtin_amdgcn_s_barrier();
    asm volatile("s_waitcnt lgkmcnt(0)" ::: "memory");
    __builtin_amdgcn_sched_barrier(0);
    __builtin_amdgcn_s_setprio(1);
#pragma unroll
    for (int ks = 0; ks < 2; ++ks)
#pragma unroll
      for (int mi = 0; mi < 4; ++mi)
#pragma unroll
        for (int ni = 0; ni < 2; ++ni)
          acc[mi][ni] = __builtin_amdgcn_mfma_f32_16x16x32_bf16(af[mi][ks], bf0[ni][ks], acc[mi][ni], 0, 0, 0);
    __builtin_amdgcn_s_setprio(0);
    __builtin_amdgcn_s_barrier();
    // ======== P2: (mq0, nq1) ========
#pragma unroll
    for (int ni = 0; ni < 2; ++ni) { bf1[ni][0] = LDB(Bc, 1, ni, 0); bf1[ni][1] = LDB(Bc, 1, ni, 1); }
    STA(Ac, 0, k2); STA(Ac, 2, k2);
    __builtin_amdgcn_s_barrier();
    asm volatile("s_waitcnt lgkmcnt(0)" ::: "memory");
    __builtin_amdgcn_sched_barrier(0);
    __builtin_amdgcn_s_setprio(1);
#pragma unroll
    for (int ks = 0; ks < 2; ++ks)
#pragma unroll
      for (int mi = 0; mi < 4; ++mi)
#pragma unroll
        for (int ni = 0; ni < 2; ++ni)
          acc[mi][2 + ni] = __builtin_amdgcn_mfma_f32_16x16x32_bf16(af[mi][ks], bf1[ni][ks], acc[mi][2 + ni], 0, 0, 0);
    __builtin_amdgcn_s_setprio(0);
    __builtin_amdgcn_s_barrier();
    // ======== P3: (mq1, nq1) ========
#pragma unroll
    for (int mi = 0; mi < 4; ++mi) { af[mi][0] = LDA(Ac, 1, mi, 0); af[mi][1] = LDA(Ac, 1, mi, 1); }
    STB(Bc, 0, 0, k2); STB(Bc, 0, 1, k2);
    __builtin_amdgcn_s_barrier();
    asm volatile("s_waitcnt lgkmcnt(0)" ::: "memory");
    __builtin_amdgcn_sched_barrier(0);
    __builtin_amdgcn_s_setprio(1);
#pragma unroll
    for (int ks = 0; ks < 2; ++ks)
#pragma unroll
      for (int mi = 0; mi < 4; ++mi)
#pragma unroll
        for (int ni = 0; ni < 2; ++ni)
          acc[4 + mi][2 + ni] = __builtin_amdgcn_mfma_f32_16x16x32_bf16(af[mi][ks], bf1[ni][ks], acc[4 + mi][2 + ni], 0, 0, 0);
    __builtin_amdgcn_s_setprio(0);
    __builtin_amdgcn_s_barrier();
    // ======== P4: (mq1, nq0) ========
    STB(Bc, 1, 0, k2); STB(Bc, 1, 1, k2);
    __builtin_amdgcn_s_barrier();
    __builtin_amdgcn_s_setprio(1);
#pragma unroll
    for (int ks = 0; ks < 2; ++ks)
#pragma unroll
      for (int mi = 0; mi < 4; ++mi)
#pragma unroll
        for (int ni = 0; ni < 2; ++ni)
          acc[4 + mi][ni] = __builtin_amdgcn_mfma_f32_16x16x32_bf16(af[mi][ks], bf0[ni][ks], acc[4 + mi][ni], 0, 0, 0);
    __builtin_amdgcn_s_setprio(0);
    asm volatile("s_waitcnt vmcnt(6)" ::: "memory");
    __builtin_amdgcn_sched_barrier(0);
    __builtin_amdgcn_s_barrier();
    // swap buffers
    uint16_t* tp = Ac; Ac = An; An = tp;
    tp = Bc; Bc = Bn; Bn = tp;
  }

  // ---- epilogue: C/D layout col=lane&15, row=(lane>>4)*4+r
#pragma unroll
  for (int gmi = 0; gmi < 8; ++gmi)
#pragma unroll
    for (int r = 0; r < 4; ++r) {
      int row = m0 + wr * 128 + gmi * 16 + g * 4 + r;
#pragma unroll
      for (int gni = 0; gni < 4; ++gni) {
        int col = n0 + wc * 64 + gni * 16 + ln16;
        if (F32OUT)
          Cf[(size_t)row * 4096 + col] = acc[gmi][gni][r];
        else
          Cb[(size_t)row * 4096 + col] = (uint16_t)f2bf(acc[gmi][gni][r]);
      }
    }
#undef STA
#undef STB
#undef LDA
#undef LDB
}

// ---------------- RoPE in-place on (B,S,H,128) bf16, short8 vectorized ----
__global__ void rope_kernel(uint16_t* __restrict__ buf,
                            const float* __restrict__ cost,
                            const float* __restrict__ sint) {
  int idx = blockIdx.x * blockDim.x + threadIdx.x;  // 2*2048*32*8 = 1048576
  int j8 = idx & 7;
  int h = (idx >> 3) & 31;
  int s = (idx >> 8) & 2047;
  int b = idx >> 19;
  size_t base = ((size_t)(b * 2048 + s)) * 4096 + h * 128 + j8 * 8;
  short8v x1 = *reinterpret_cast<const short8v*>(buf + base);
  short8v x2 = *reinterpret_cast<const short8v*>(buf + base + 64);
  float4 c0 = *reinterpret_cast<const float4*>(cost + s * 64 + j8 * 8);
  float4 c1 = *reinterpret_cast<const float4*>(cost + s * 64 + j8 * 8 + 4);
  float4 s0 = *reinterpret_cast<const float4*>(sint + s * 64 + j8 * 8);
  float4 s1 = *reinterpret_cast<const float4*>(sint + s * 64 + j8 * 8 + 4);
  float c[8] = {c0.x, c0.y, c0.z, c0.w, c1.x, c1.y, c1.z, c1.w};
  float sn[8] = {s0.x, s0.y, s0.z, s0.w, s1.x, s1.y, s1.z, s1.w};
  short8v o1, o2;
#pragma unroll
  for (int e = 0; e < 8; ++e) {
    float a = bf2f((uint16_t)x1[e]);
    float bb = bf2f((uint16_t)x2[e]);
    o1[e] = (short)f2bf(a * c[e] - bb * sn[e]);
    o2[e] = (short)f2bf(bb * c[e] + a * sn[e]);
  }
  *reinterpret_cast<short8v*>(buf + base) = o1;
  *reinterpret_cast<short8v*>(buf + base + 64) = o2;
}

// ---------------- causal flash attention, 32x32 swapped-QK^T -------------
// 4 waves x 32 q-rows, uniform pairing (block p does q-tiles 15-p then p
// = 34 K-tiles), double-buffered K/V LDS, 1 barrier/tile, K staged via
// global_load_lds (pre-swizzled source), V reg-staged. RoPE-on-Q fused
// with scale*log2e folded in.
__global__ __launch_bounds__(256, 2) void flash_kernel(
    const uint16_t* __restrict__ Q, const uint16_t* __restrict__ K,
    const uint16_t* __restrict__ V, uint16_t* __restrict__ O,
    const float* __restrict__ cost, const float* __restrict__ sint) {
  constexpr int S = 2048, HID = 4096;
  __shared__ uint16_t Ks[2][64 * 128];   // [k][d], swizzled
  __shared__ uint16_t Vt[2][128 * 64];   // [d][k] transposed, swizzled

  const int tid = threadIdx.x;
  const int lane = tid & 63, w = tid >> 6;
  const int l31 = lane & 31, hi = lane >> 5;
  const int bh = blockIdx.x;            // bh fastest -> same head same XCD
  const int b = bh >> 5, h = bh & 31;
  const int pr = blockIdx.y;            // pair id 0..7
  const size_t base = (size_t)b * S * HID + (size_t)h * 128;
  const int swz = (l31 & 7) << 3;       // frag-read swizzle for this lane

  // ---- K staging via gload_lds: instr i stages rows w*16+i*4..+3.
  const int kr_g = lane >> 4;                       // row-in-group 0..3
  const int kre = w * 16 + kr_g;                    // rows for i even
  const int kro = w * 16 + 4 + kr_g;                // rows for i odd
  const uint16_t* kse = K + base + (size_t)kre * HID + (((lane & 15) ^ (kr_g & 7)) * 8);
  const uint16_t* kso = K + base + (size_t)kro * HID + (((lane & 15) ^ ((4 + kr_g) & 7)) * 8);
  // V staging geometry (reg transpose)
  const int vk4 = tid & 15;        // k/4
  const int vdc = tid >> 4;        // d-chunk (0..15)

#define STAGEK(dst, kb0)                                                     \
  do {                                                                       \
    gload_lds16(kse + (size_t)(kb0) * HID,       (dst) + (w * 16 + 0) * 128);  \
    gload_lds16(kso + (size_t)(kb0) * HID,       (dst) + (w * 16 + 4) * 128);  \
    gload_lds16(kse + (size_t)((kb0) + 8) * HID, (dst) + (w * 16 + 8) * 128);  \
    gload_lds16(kso + (size_t)((kb0) + 8) * HID, (dst) + (w * 16 + 12) * 128); \
  } while (0)

  const float cl2e = 0.12751025f;  // (1/sqrt(128)) * log2(e), folded into Q

  for (int pass = 0; pass < 2; ++pass) {
    const int bt = pass ? pr : 15 - pr;   // long q-tile first
    const int q0 = bt * 128;
    const int q0w = q0 + w * 32;

    // ---- Q frags, fused RoPE x (scale*log2e)
    short8v qf[8];
    {
      const int srow = q0w + l31;
      const uint16_t* qrow = Q + base + (size_t)srow * HID + hi * 8;
      const float* cr = cost + srow * 64 + hi * 8;
      const float* sr = sint + srow * 64 + hi * 8;
#pragma unroll
      for (int c = 0; c < 4; ++c) {
        short8v x1 = *reinterpret_cast<const short8v*>(qrow + c * 16);
        short8v x2 = *reinterpret_cast<const short8v*>(qrow + 64 + c * 16);
        float4 cA = *reinterpret_cast<const float4*>(cr + c * 16);
        float4 cB = *reinterpret_cast<const float4*>(cr + c * 16 + 4);
        float4 sA = *reinterpret_cast<const float4*>(sr + c * 16);
        float4 sB = *reinterpret_cast<const float4*>(sr + c * 16 + 4);
        float cc[8] = {cA.x, cA.y, cA.z, cA.w, cB.x, cB.y, cB.z, cB.w};
        float ss[8] = {sA.x, sA.y, sA.z, sA.w, sB.x, sB.y, sB.z, sB.w};
        short8v o1, o2;
#pragma unroll
        for (int e = 0; e < 8; ++e) {
          float a = bf2f((uint16_t)x1[e]) * cl2e;
          float bb = bf2f((uint16_t)x2[e]) * cl2e;
          o1[e] = (short)f2bf(a * cc[e] - bb * ss[e]);
          o2[e] = (short)f2bf(bb * cc[e] + a * ss[e]);
        }
        qf[c] = o1; qf[c + 4] = o2;
      }
    }

    f32x16 o[4];
#pragma unroll
    for (int db = 0; db < 4; ++db)
#pragma unroll
      for (int r = 0; r < 16; ++r) o[db][r] = 0.f;
    float m_run = -1e30f, l_run = 0.f;

    short8v vp[4];  // V prefetch registers

    // ---- prologue: stage tile 0 into buffer 0
    STAGEK(&Ks[0][0], 0);
#pragma unroll
    for (int j = 0; j < 4; ++j)
      vp[j] = *reinterpret_cast<const short8v*>(
          V + base + (size_t)(4 * vk4 + j) * HID + vdc * 8);
#pragma unroll
    for (int e = 0; e < 8; ++e) {
      int row = vdc * 8 + e;
      short4v pk; pk[0] = vp[0][e]; pk[1] = vp[1][e]; pk[2] = vp[2][e]; pk[3] = vp[3][e];
      *reinterpret_cast<short4v*>(&Vt[0][0] + row * 64 + ((vk4 * 4) ^ ((row & 7) << 3))) = pk;
    }
    __syncthreads();

    const int ntiles = bt * 2 + 2;
    for (int kt = 0; kt < ntiles; ++kt) {
      const int kb = kt * 64;
      const bool havenext = (kt + 1 < ntiles);
      uint16_t* ksc = &Ks[kt & 1][0];
      uint16_t* vtc = &Vt[kt & 1][0];
      uint16_t* ksn = &Ks[(kt + 1) & 1][0];
      uint16_t* vtn = &Vt[(kt + 1) & 1][0];
      // ---- stage next tile: K async -> LDS[nxt]; V global -> regs
      if (havenext) {
        STAGEK(ksn, kb + 64);
#pragma unroll
        for (int j = 0; j < 4; ++j)
          vp[j] = *reinterpret_cast<const short8v*>(
              V + base + (size_t)(kb + 64 + 4 * vk4 + j) * HID + vdc * 8);
      }

      if (kb <= q0w + 31) {
        f32x16 s0, s1;
#pragma unroll
        for (int r = 0; r < 16; ++r) { s0[r] = 0.f; s1[r] = 0.f; }
        __builtin_amdgcn_s_setprio(1);
#pragma unroll
        for (int c = 0; c < 8; ++c) {
          int col = c * 16 + hi * 8;
          short8v kf0 = *reinterpret_cast<const short8v*>(ksc + l31 * 128 + (col ^ swz));
          short8v kf1 = *reinterpret_cast<const short8v*>(ksc + (32 + l31) * 128 + (col ^ swz));
          s0 = __builtin_amdgcn_mfma_f32_32x32x16_bf16(kf0, qf[c], s0, 0, 0, 0);
          s1 = __builtin_amdgcn_mfma_f32_32x32x16_bf16(kf1, qf[c], s1, 0, 0, 0);
        }
        __builtin_amdgcn_s_setprio(0);
        // (scores already in exp2 domain - scale folded into Q)
        if (kb + 63 > q0w) {
          const int qg = q0w + l31;
#pragma unroll
          for (int r = 0; r < 16; ++r) {
            int kl = (r & 3) + 8 * (r >> 2) + 4 * hi;
            if (kb + kl > qg) s0[r] = -1e30f;
            if (kb + 32 + kl > qg) s1[r] = -1e30f;
          }
        }
        float mx = s0[0];
#pragma unroll
        for (int r = 1; r < 16; ++r) mx = fmaxf(mx, s0[r]);
#pragma unroll
        for (int r = 0; r < 16; ++r) mx = fmaxf(mx, s1[r]);
        mx = fmaxf(mx, __shfl_xor(mx, 32));
        if (__any(mx > m_run + 8.0f)) {  // defer-max (T13)
          float nm = fmaxf(m_run, mx);
          float f = __builtin_amdgcn_exp2f(m_run - nm);
          l_run *= f;
#pragma unroll
          for (int db = 0; db < 4; ++db)
#pragma unroll
            for (int r = 0; r < 16; ++r) o[db][r] *= f;
          m_run = nm;
        }
        float rs = 0.f;
#pragma unroll
        for (int r = 0; r < 16; ++r) { s0[r] = __builtin_amdgcn_exp2f(s0[r] - m_run); rs += s0[r]; }
#pragma unroll
        for (int r = 0; r < 16; ++r) { s1[r] = __builtin_amdgcn_exp2f(s1[r] - m_run); rs += s1[r]; }
        rs += __shfl_xor(rs, 32);
        l_run += rs;
        uint32_t c0[8], c1[8];
#pragma unroll
        for (int i = 0; i < 4; ++i) {
          asm("v_cvt_pk_bf16_f32 %0, %1, %2" : "=v"(c0[i])     : "v"(s0[4 * i]),     "v"(s0[4 * i + 1]));
          asm("v_cvt_pk_bf16_f32 %0, %1, %2" : "=v"(c1[i])     : "v"(s0[4 * i + 2]), "v"(s0[4 * i + 3]));
          asm("v_cvt_pk_bf16_f32 %0, %1, %2" : "=v"(c0[4 + i]) : "v"(s1[4 * i]),     "v"(s1[4 * i + 1]));
          asm("v_cvt_pk_bf16_f32 %0, %1, %2" : "=v"(c1[4 + i]) : "v"(s1[4 * i + 2]), "v"(s1[4 * i + 3]));
        }
        short8v pa[4];
#pragma unroll
        for (int t = 0; t < 4; ++t) {
          int st = t >> 1, ts = t & 1;
          uint32_t a0 = c0[st * 4 + 2 * ts],     a1 = c1[st * 4 + 2 * ts];
          uint32_t b0 = c0[st * 4 + 2 * ts + 1], b1 = c1[st * 4 + 2 * ts + 1];
          uint32_t sb0 = (uint32_t)__shfl_xor((int)b0, 32);
          uint32_t sb1 = (uint32_t)__shfl_xor((int)b1, 32);
          uint32_t sa0 = (uint32_t)__shfl_xor((int)a0, 32);
          uint32_t sa1 = (uint32_t)__shfl_xor((int)a1, 32);
          union { uint32_t u[4]; short8v v; } pk;
          pk.u[0] = hi ? sb0 : a0;
          pk.u[1] = hi ? sb1 : a1;
          pk.u[2] = hi ? b0 : sa0;
          pk.u[3] = hi ? b1 : sa1;
          pa[t] = pk.v;
        }
        __builtin_amdgcn_s_setprio(1);
#pragma unroll
        for (int t = 0; t < 4; ++t) {
          int col = t * 16 + hi * 8;
#pragma unroll
          for (int db = 0; db < 4; ++db) {
            short8v vf = *reinterpret_cast<const short8v*>(
                vtc + (db * 32 + l31) * 64 + (col ^ swz));
            o[db] = __builtin_amdgcn_mfma_f32_32x32x16_bf16(vf, pa[t], o[db], 0, 0, 0);
          }
        }
        __builtin_amdgcn_s_setprio(0);
      }
      // ---- write prefetched V into the other buffer
      if (havenext) {
#pragma unroll
        for (int e = 0; e < 8; ++e) {
          int row = vdc * 8 + e;
          short4v pk; pk[0] = vp[0][e]; pk[1] = vp[1][e]; pk[2] = vp[2][e]; pk[3] = vp[3][e];
          *reinterpret_cast<short4v*>(vtn + row * 64 + ((vk4 * 4) ^ ((row & 7) << 3))) = pk;
        }
      }
      __syncthreads();  // one barrier per tile (drains gload_lds + ds_writes)
    }

    float inv = 1.f / l_run;
    uint16_t* orow = O + base + (size_t)(q0w + l31) * HID;
#pragma unroll
    for (int db = 0; db < 4; ++db)
#pragma unroll
      for (int rq = 0; rq < 4; ++rq) {
        short4v st4;
#pragma unroll
        for (int e = 0; e < 4; ++e) st4[e] = (short)f2bf(o[db][rq * 4 + e] * inv);
        *reinterpret_cast<short4v*>(orow + db * 32 + rq * 8 + hi * 4) = st4;
      }
  }
#undef STAGEK
}

// ---------------- launch ----------------
extern "C" void kernel_launch(void* const* d_in, const int* in_sizes, int n_in,
                              void* d_out, int out_size, void* d_ws, size_t ws_size,
                              hipStream_t stream) {
  const float* x    = (const float*)d_in[0];
  const float* cosb = (const float*)d_in[1];
  const float* sinb = (const float*)d_in[2];
  const float* wq   = (const float*)d_in[3];
  const float* wk   = (const float*)d_in[4];
  const float* wv   = (const float*)d_in[5];
  const float* wo   = (const float*)d_in[6];
  float* out = (float*)d_out;

  const size_t BUF = 33554432;  // 16.7M bf16 elements = 32 MiB
  if (ws_size < 8 * BUF) return;
  char* ws = (char*)d_ws;
  uint16_t* xb  = (uint16_t*)(ws + 0 * BUF);  // also reused as attn-out
  uint16_t* wqb = (uint16_t*)(ws + 1 * BUF);  // wqb/wkb/wvb contiguous
  uint16_t* wkb = (uint16_t*)(ws + 2 * BUF);
  uint16_t* wvb = (uint16_t*)(ws + 3 * BUF);
  uint16_t* wob = (uint16_t*)(ws + 4 * BUF);
  uint16_t* qb  = (uint16_t*)(ws + 5 * BUF);  // qb/kb/vb contiguous
  uint16_t* kb  = (uint16_t*)(ws + 6 * BUF);
  uint16_t* vb  = (uint16_t*)(ws + 7 * BUF);
  uint16_t* ab  = xb;

  const int nElem = 2 * 2048 * 4096;  // 16,777,216 (= 4096*4096 too)
  dim3 cgrid(nElem / 4 / 256, 5);
  convert5_kernel<<<cgrid, 256, 0, stream>>>(x, wq, wk, wv, wo,
                                             xb, wqb, wkb, wvb, wob, nElem / 4);

  // QKV projections: one 3D dispatch, z = {q,k,v} slice (per-slice locality)
  dim3 gqkv(16, 16, 3), gblk(512);
  gemm256_kernel<0><<<gqkv, gblk, 0, stream>>>(xb, wqb, nullptr, qb, 4096, 4096, 4096);

  // RoPE only on K (Q rope fused into flash)
  dim3 rgrid(1048576 / 256);
  rope_kernel<<<rgrid, 256, 0, stream>>>(kb, cosb, sinb);

  dim3 fgrid(64, 8);  // (B*H fastest, q-tile pairs): head -> one XCD
  flash_kernel<<<fgrid, 256, 0, stream>>>(qb, kb, vb, ab, cosb, sinb);

  dim3 ggrid(16, 16, 1);
  gemm256_kernel<1><<<ggrid, gblk, 0, stream>>>(ab, wob, out, nullptr, 4096, 4096, 4096);
}